// Round 9
// baseline (142.218 us; speedup 1.0000x reference)
//
#include <hip/hip_runtime.h>
#include <hip/hip_bf16.h>

#define NPIX (8*128*128)   // 131072 pixels
#define CH   256

typedef __attribute__((ext_vector_type(8))) short bf16x8;
typedef __attribute__((ext_vector_type(4))) float f32x4;

__device__ inline unsigned int pkbf(float a, float b) {
    union { __hip_bfloat162 h; unsigned int u; } c;
    c.h = __float22bfloat162_rn(float2{a, b});
    return c.u;
}
__device__ inline unsigned short f2bf(float f) {
    unsigned int u = __float_as_uint(f);
    return (unsigned short)((u + 0x7FFFu + ((u >> 16) & 1u)) >> 16);  // RNE
}
// within-32-chunk K permutation: k = chunk + nf*16 + lm  ->  chunk + lm*2 + nf
__device__ inline int kperm32(int k) {
    return (k & ~31) | ((k & 15) << 1) | ((k >> 4) & 1);
}

// W2 [256][256]->bf16 with K-permuted columns; W1 [256][12]->bf16 padded [256][16];
// W4 [3][256]->bf16 padded [16][256] (rows 3..15 zero), K-permuted columns.
__global__ __launch_bounds__(256) void conv_weights(
    const float* __restrict__ W1, const float* __restrict__ W2,
    const float* __restrict__ W4,
    unsigned short* __restrict__ W2b, unsigned short* __restrict__ W1b,
    unsigned short* __restrict__ W4b)
{
    if (blockIdx.x < 256) {
        const int o = blockIdx.x, k = threadIdx.x;
        W2b[o*CH + kperm32(k)] = f2bf(W2[o*CH + k]);
    } else {
        const int t = threadIdx.x;
        #pragma unroll
        for (int j = 0; j < 16; ++j)
            W1b[t*16 + j] = (j < 12) ? f2bf(W1[t*12 + j]) : (unsigned short)0;
        const int kp = kperm32(t);
        #pragma unroll
        for (int r = 0; r < 16; ++r)
            W4b[r*CH + kp] = (r < 3) ? f2bf(W4[r*CH + t]) : (unsigned short)0;
    }
}

// Fused SIREN 12->256->256->3, all matmuls MFMA (PRE path).
// 512 threads = 8 waves, 64 pixels/block; wave w owns out-ch chunk [32w, 32w+32).
// W2 panel (16 B-frags = 64 VGPR) hoisted to registers at kernel top -> layer-2
// K-loop is pure {ds_read + MFMA}. Layer 4 split across all 8 waves (k-slice =
// wave), partials reduced via LDS overlaid on the dead x-staging region.
// h [64 pix][256 k'] bf16 LDS (32 KB), K'-permuted, XOR-swizzled (pix&31)<<4.
template<bool PRE>
__global__ __launch_bounds__(512, 3) void rendernet4(
    const float* __restrict__ z,
    const float* __restrict__ nrm,
    const float* __restrict__ sph,
    const float* __restrict__ pc,
    const float* __restrict__ vd,
    const float* __restrict__ W1,
    const float* __restrict__ b1,
    const float* __restrict__ W2f,
    const unsigned short* __restrict__ W2b,
    const unsigned short* __restrict__ W1b,
    const float* __restrict__ b2,
    const float* __restrict__ W4f,
    const unsigned short* __restrict__ W4b,
    const float* __restrict__ b4,
    float* __restrict__ out)
{
    __shared__ __align__(16) char smem[64*512 + 6144];   // 32 KB h + 6 KB x/red union
    char*  xb    = smem + 64*512;             // x staging: 64 rows x 80 B (5120 B)
    float* red_f = (float*)(smem + 64*512);   // L4 partials: [8][3][64] f32 (6144 B)

    const int tid     = threadIdx.x;
    const int lane    = tid & 63;
    const int wave    = tid >> 6;      // 0..7
    const int lm      = lane & 15;     // A row / B,D col
    const int lg      = lane >> 4;     // k-group of 8 / D row-group of 4
    const int n0      = wave * 32;     // this wave's 32-channel chunk
    const int pixbase = blockIdx.x * 64;

    // ---- z preload (used only by the 192 reducer threads at the very end) ----
    float zv = 0.0f;
    if (tid < 192) zv = z[(tid >> 6)*NPIX + pixbase + (tid & 63)];

    // ---- W2 B-fragment hoist: issue all 16 loads now, consume in layer 2 ----
    bf16x8 w2r[16];
    if constexpr (PRE) {
        const unsigned short* bp = W2b + (n0 + lm)*CH + lg*8;
        #pragma unroll
        for (int k0i = 0; k0i < 8; ++k0i)
            #pragma unroll
            for (int nf = 0; nf < 2; ++nf)
                w2r[k0i*2 + nf] = *(const bf16x8*)(bp + nf*16*CH + k0i*32);
    }

    f32x4 acc[4][2];

    // ================= layer 1 =================
    if constexpr (PRE) {
        // stage x[64 pix][32 k] bf16: wave = 4-channel slot (slots 3..7 zero pad)
        {
            const int gp = pixbase + lane;
            unsigned int w0 = 0u, w1 = 0u;
            if (wave == 0) {
                w0 = pkbf(sph[0*NPIX+gp], sph[1*NPIX+gp]);
                w1 = pkbf(sph[2*NPIX+gp], nrm[0*NPIX+gp]);
            } else if (wave == 1) {
                w0 = pkbf(nrm[1*NPIX+gp], nrm[2*NPIX+gp]);
                w1 = pkbf(pc [0*NPIX+gp], pc [1*NPIX+gp]);
            } else if (wave == 2) {
                w0 = pkbf(pc[2*NPIX+gp], vd[0*NPIX+gp]);
                w1 = pkbf(vd[1*NPIX+gp], vd[2*NPIX+gp]);
            }
            *(unsigned int*)(xb + lane*80 + wave*8)     = w0;
            *(unsigned int*)(xb + lane*80 + wave*8 + 4) = w1;
        }
        __syncthreads();

        #pragma unroll
        for (int nf = 0; nf < 2; ++nf) {
            const float bv = b1[n0 + nf*16 + lm];
            #pragma unroll
            for (int mf = 0; mf < 4; ++mf) acc[mf][nf] = (f32x4){bv, bv, bv, bv};
        }

        bf16x8 w1f[2];
        #pragma unroll
        for (int nf = 0; nf < 2; ++nf) {
            bf16x8 t = *(const bf16x8*)(W1b + (n0 + nf*16 + lm)*16 + (lg & 1)*8);
            w1f[nf] = (lg < 2) ? t : (bf16x8){0,0,0,0,0,0,0,0};
        }
        bf16x8 ax[4];
        #pragma unroll
        for (int mf = 0; mf < 4; ++mf)
            ax[mf] = *(const bf16x8*)(xb + (mf*16 + lm)*80 + lg*16);

        #pragma unroll
        for (int nf = 0; nf < 2; ++nf)
            #pragma unroll
            for (int mf = 0; mf < 4; ++mf)
                acc[mf][nf] = __builtin_amdgcn_mfma_f32_16x16x32_bf16(
                                  ax[mf], w1f[nf], acc[mf][nf], 0, 0, 0);

        // h1 = sin(30*acc) -> packed pair write (k' = n0 + lm*2 + {0,1})
        #pragma unroll
        for (int mf = 0; mf < 4; ++mf)
            #pragma unroll
            for (int r = 0; r < 4; ++r) {
                const int pix = mf*16 + lg*4 + r;
                const unsigned int pk = pkbf(__sinf(30.0f*acc[mf][0][r]),
                                             __sinf(30.0f*acc[mf][1][r]));
                *(unsigned int*)(smem + pix*512 + ((n0*2 + lm*4) ^ ((pix & 31) << 4))) = pk;
            }
    } else {
        // fallback: fp32 VALU layer 1, direct permuted h1 writes (pix = lane)
        const int gp = pixbase + lane;
        float xv[12];
        #pragma unroll
        for (int k = 0; k < 3; ++k) xv[k]     = sph[k*NPIX + gp];
        #pragma unroll
        for (int k = 0; k < 3; ++k) xv[3 + k] = nrm[k*NPIX + gp];
        #pragma unroll
        for (int k = 0; k < 3; ++k) xv[6 + k] = pc [k*NPIX + gp];
        #pragma unroll
        for (int k = 0; k < 3; ++k) xv[9 + k] = vd [k*NPIX + gp];
        #pragma unroll
        for (int c = 0; c < 32; ++c) {
            const int cc = n0 + c;
            float a = b1[cc];
            #pragma unroll
            for (int k = 0; k < 12; ++k) a += W1[cc*12 + k] * xv[k];
            const int kp = n0 + ((c & 15) << 1) + (c >> 4);
            *(unsigned short*)(smem + lane*512 + ((kp*2) ^ ((lane & 31) << 4))) =
                f2bf(__sinf(30.0f * a));
        }
    }
    __syncthreads();

    // ================= layer 2: K-loop (K'=256), pure LDS + register MFMA =================
    #pragma unroll
    for (int nf = 0; nf < 2; ++nf) {
        const float bv = b2[n0 + nf*16 + lm];
        #pragma unroll
        for (int mf = 0; mf < 4; ++mf) acc[mf][nf] = (f32x4){bv, bv, bv, bv};
    }

    if constexpr (PRE) {
        #pragma unroll
        for (int k0i = 0; k0i < 8; ++k0i) {
            bf16x8 afr[4];
            #pragma unroll
            for (int mf = 0; mf < 4; ++mf) {
                const int pr = mf*16 + lm;
                afr[mf] = *(const bf16x8*)(smem + pr*512 +
                              ((k0i*64 + lg*16) ^ ((pr & 31) << 4)));
            }
            #pragma unroll
            for (int nf = 0; nf < 2; ++nf)
                #pragma unroll
                for (int mf = 0; mf < 4; ++mf)
                    acc[mf][nf] = __builtin_amdgcn_mfma_f32_16x16x32_bf16(
                                      afr[mf], w2r[k0i*2 + nf], acc[mf][nf], 0, 0, 0);
        }
    } else {
        #pragma unroll
        for (int k0i = 0; k0i < 8; ++k0i) {
            bf16x8 afr[4];
            #pragma unroll
            for (int mf = 0; mf < 4; ++mf) {
                const int pr = mf*16 + lm;
                afr[mf] = *(const bf16x8*)(smem + pr*512 +
                              ((k0i*64 + lg*16) ^ ((pr & 31) << 4)));
            }
            #pragma unroll
            for (int nf = 0; nf < 2; ++nf) {
                bf16x8 t;
                #pragma unroll
                for (int j = 0; j < 8; ++j) {
                    const int kp = k0i*32 + lg*8 + j;
                    const int kr = (kp & ~31) | ((kp & 1) << 4) | ((kp >> 1) & 15);
                    t[j] = (short)f2bf(W2f[(n0 + nf*16 + lm)*CH + kr]);
                }
                #pragma unroll
                for (int mf = 0; mf < 4; ++mf)
                    acc[mf][nf] = __builtin_amdgcn_mfma_f32_16x16x32_bf16(
                                      afr[mf], t, acc[mf][nf], 0, 0, 0);
            }
        }
    }
    __syncthreads();   // all h1 reads done

    // ================= h2 = sin(30*acc) -> packed pair write =================
    #pragma unroll
    for (int mf = 0; mf < 4; ++mf)
        #pragma unroll
        for (int r = 0; r < 4; ++r) {
            const int pix = mf*16 + lg*4 + r;
            const unsigned int pk = pkbf(__sinf(30.0f*acc[mf][0][r]),
                                         __sinf(30.0f*acc[mf][1][r]));
            *(unsigned int*)(smem + pix*512 + ((n0*2 + lm*4) ^ ((pix & 31) << 4))) = pk;
        }
    __syncthreads();

    // ================= layer 4: split across waves, k-slice = wave =================
    {
        bf16x8 b4f;
        if constexpr (PRE) {
            b4f = *(const bf16x8*)(W4b + lm*CH + wave*32 + lg*8);  // rows 3..15 zero
        } else {
            #pragma unroll
            for (int j = 0; j < 8; ++j) {
                const int kp = wave*32 + lg*8 + j;
                const int kr = (kp & ~31) | ((kp & 1) << 4) | ((kp >> 1) & 15);
                b4f[j] = (lm < 3) ? (short)f2bf(W4f[lm*CH + kr]) : (short)0;
            }
        }
        f32x4 d[4];
        #pragma unroll
        for (int mf = 0; mf < 4; ++mf) d[mf] = (f32x4){0.f, 0.f, 0.f, 0.f};

        bf16x8 afr[4];
        #pragma unroll
        for (int mf = 0; mf < 4; ++mf) {
            const int pr = mf*16 + lm;
            afr[mf] = *(const bf16x8*)(smem + pr*512 +
                          ((wave*64 + lg*16) ^ ((pr & 31) << 4)));
        }
        #pragma unroll
        for (int mf = 0; mf < 4; ++mf)
            d[mf] = __builtin_amdgcn_mfma_f32_16x16x32_bf16(afr[mf], b4f, d[mf], 0, 0, 0);

        if (lm < 3) {
            #pragma unroll
            for (int mf = 0; mf < 4; ++mf)
                #pragma unroll
                for (int r = 0; r < 4; ++r) {
                    const int pix = mf*16 + lg*4 + r;
                    red_f[wave*192 + lm*64 + pix] = d[mf][r];
                }
        }
    }
    __syncthreads();

    // ================= cross-wave reduce + residual (192 threads) =================
    if (tid < 192) {
        float t = 0.f;
        #pragma unroll
        for (int w = 0; w < 8; ++w) t += red_f[w*192 + tid];
        const int c3 = tid >> 6, p = tid & 63;
        out[c3*NPIX + pixbase + p] = zv + 0.5f * __sinf(30.0f * (t + b4[c3]));
    }
}

extern "C" void kernel_launch(void* const* d_in, const int* in_sizes, int n_in,
                              void* d_out, int out_size, void* d_ws, size_t ws_size,
                              hipStream_t stream) {
    const float* z   = (const float*)d_in[0];
    const float* nrm = (const float*)d_in[1];
    // d_in[2] = ad : unused by the reference
    const float* s   = (const float*)d_in[3];
    const float* pc  = (const float*)d_in[4];
    const float* vd  = (const float*)d_in[5];
    const float* W1  = (const float*)d_in[6];
    const float* b1  = (const float*)d_in[7];
    const float* W2  = (const float*)d_in[8];
    const float* b2  = (const float*)d_in[9];
    const float* W4  = (const float*)d_in[10];
    const float* b4  = (const float*)d_in[11];
    float* out = (float*)d_out;

    const size_t need = (size_t)(CH*CH + 16*CH + 16*CH) * sizeof(unsigned short); // 144 KB
    if (ws_size >= need) {
        unsigned short* W2b = (unsigned short*)d_ws;
        unsigned short* W1b = W2b + CH*CH;
        unsigned short* W4b = W1b + 16*CH;
        conv_weights<<<dim3(257), dim3(256), 0, stream>>>(W1, W2, W4, W2b, W1b, W4b);
        rendernet4<true><<<dim3(NPIX/64), dim3(512), 0, stream>>>(
            z, nrm, s, pc, vd, W1, b1, W2, W2b, W1b, b2, W4, W4b, b4, out);
    } else {
        rendernet4<false><<<dim3(NPIX/64), dim3(512), 0, stream>>>(
            z, nrm, s, pc, vd, W1, b1, W2, nullptr, nullptr, b2, W4, nullptr, b4, out);
    }
}

// Round 10
// 122.718 us; speedup vs baseline: 1.1589x; 1.1589x over previous
//
#include <hip/hip_runtime.h>
#include <hip/hip_bf16.h>

#define NPIX (8*128*128)   // 131072 pixels
#define CH   256
#define SCALE 4.774648292756860f   // 30 / (2*pi): folds sin(30*x) arg into revolutions

typedef __attribute__((ext_vector_type(8))) short bf16x8;
typedef __attribute__((ext_vector_type(4))) float f32x4;

__device__ inline unsigned int pkbf(float a, float b) {
    union { __hip_bfloat162 h; unsigned int u; } c;
    c.h = __float22bfloat162_rn(float2{a, b});
    return c.u;
}
__device__ inline unsigned short f2bf(float f) {
    unsigned int u = __float_as_uint(f);
    return (unsigned short)((u + 0x7FFFu + ((u >> 16) & 1u)) >> 16);  // RNE
}
// sin(2*pi*t): v_fract_f32 + v_sin_f32 (2 instrs; v_sin takes revolutions)
__device__ inline float sinrev(float t) {
    return __builtin_amdgcn_sinf(__builtin_amdgcn_fractf(t));
}
// within-32-chunk K permutation: k = chunk + nf*16 + lm  ->  chunk + lm*2 + nf
__device__ inline int kperm32(int k) {
    return (k & ~31) | ((k & 15) << 1) | ((k >> 4) & 1);
}

// Weights -> bf16, PRE-SCALED by 30/(2pi) so MFMA output is in revolutions.
// W2 [256][256] K-permuted cols; W1 [256][12] padded [256][16]; W4 [3][256]
// padded [16][256] (rows 3..15 zero), K-permuted cols.
__global__ __launch_bounds__(256) void conv_weights(
    const float* __restrict__ W1, const float* __restrict__ W2,
    const float* __restrict__ W4,
    unsigned short* __restrict__ W2b, unsigned short* __restrict__ W1b,
    unsigned short* __restrict__ W4b)
{
    if (blockIdx.x < 256) {
        const int o = blockIdx.x, k = threadIdx.x;
        W2b[o*CH + kperm32(k)] = f2bf(W2[o*CH + k] * SCALE);
    } else {
        const int t = threadIdx.x;
        #pragma unroll
        for (int j = 0; j < 16; ++j)
            W1b[t*16 + j] = (j < 12) ? f2bf(W1[t*12 + j] * SCALE) : (unsigned short)0;
        const int kp = kperm32(t);
        #pragma unroll
        for (int r = 0; r < 16; ++r)
            W4b[r*CH + kp] = (r < 3) ? f2bf(W4[r*CH + t] * SCALE) : (unsigned short)0;
    }
}

// Fused SIREN 12->256->256->3, all matmuls MFMA (PRE path). R7 structure:
// 512 threads = 8 waves, 64 pixels/block; wave w owns out-ch chunk [32w, 32w+32).
// h [64 pix][256 k'] bf16 LDS (32 KB), K'-permuted, XOR-swizzled (pix&31)<<4.
// x [64 pix][32 k] bf16 LDS rows padded to 80 B. acc 4x2 (32 regs).
// Activation: weights pre-scaled -> sin is fract+v_sin (2 ops, no muls).
template<bool PRE>
__global__ __launch_bounds__(512, 4) void rendernet5(
    const float* __restrict__ z,
    const float* __restrict__ nrm,
    const float* __restrict__ sph,
    const float* __restrict__ pc,
    const float* __restrict__ vd,
    const float* __restrict__ W1,
    const float* __restrict__ b1,
    const float* __restrict__ W2f,
    const unsigned short* __restrict__ W2b,
    const unsigned short* __restrict__ W1b,
    const float* __restrict__ b2,
    const float* __restrict__ W4f,
    const unsigned short* __restrict__ W4b,
    const float* __restrict__ b4,
    float* __restrict__ out)
{
    __shared__ __align__(16) char smem[64*512 + 64*80];   // 32 KB h + 5 KB x
    char* xb = smem + 64*512;

    const int tid     = threadIdx.x;
    const int lane    = tid & 63;
    const int wave    = tid >> 6;      // 0..7
    const int lm      = lane & 15;     // A row / B,D col
    const int lg      = lane >> 4;     // k-group of 8 / D row-group of 4
    const int n0      = wave * 32;     // this wave's 32-channel chunk
    const int pixbase = blockIdx.x * 64;

    f32x4 acc[4][2];

    // ================= layer 1 =================
    if constexpr (PRE) {
        // stage x[64 pix][32 k] bf16: wave = 4-channel slot (slots 3..7 zero pad)
        {
            const int gp = pixbase + lane;
            unsigned int w0 = 0u, w1 = 0u;
            if (wave == 0) {
                w0 = pkbf(sph[0*NPIX+gp], sph[1*NPIX+gp]);
                w1 = pkbf(sph[2*NPIX+gp], nrm[0*NPIX+gp]);
            } else if (wave == 1) {
                w0 = pkbf(nrm[1*NPIX+gp], nrm[2*NPIX+gp]);
                w1 = pkbf(pc [0*NPIX+gp], pc [1*NPIX+gp]);
            } else if (wave == 2) {
                w0 = pkbf(pc[2*NPIX+gp], vd[0*NPIX+gp]);
                w1 = pkbf(vd[1*NPIX+gp], vd[2*NPIX+gp]);
            }
            *(unsigned int*)(xb + lane*80 + wave*8)     = w0;
            *(unsigned int*)(xb + lane*80 + wave*8 + 4) = w1;
        }
        __syncthreads();

        // bias-preloaded accumulators (scaled to revolutions)
        #pragma unroll
        for (int nf = 0; nf < 2; ++nf) {
            const float bv = b1[n0 + nf*16 + lm] * SCALE;
            #pragma unroll
            for (int mf = 0; mf < 4; ++mf) acc[mf][nf] = (f32x4){bv, bv, bv, bv};
        }

        bf16x8 w1f[2];
        #pragma unroll
        for (int nf = 0; nf < 2; ++nf) {
            bf16x8 t = *(const bf16x8*)(W1b + (n0 + nf*16 + lm)*16 + (lg & 1)*8);
            w1f[nf] = (lg < 2) ? t : (bf16x8){0,0,0,0,0,0,0,0};
        }
        bf16x8 ax[4];
        #pragma unroll
        for (int mf = 0; mf < 4; ++mf)
            ax[mf] = *(const bf16x8*)(xb + (mf*16 + lm)*80 + lg*16);

        #pragma unroll
        for (int nf = 0; nf < 2; ++nf)
            #pragma unroll
            for (int mf = 0; mf < 4; ++mf)
                acc[mf][nf] = __builtin_amdgcn_mfma_f32_16x16x32_bf16(
                                  ax[mf], w1f[nf], acc[mf][nf], 0, 0, 0);

        // h1 = sin(2pi*acc) -> packed pair write (k' = n0 + lm*2 + {0,1})
        #pragma unroll
        for (int mf = 0; mf < 4; ++mf)
            #pragma unroll
            for (int r = 0; r < 4; ++r) {
                const int pix = mf*16 + lg*4 + r;
                const unsigned int pk = pkbf(sinrev(acc[mf][0][r]),
                                             sinrev(acc[mf][1][r]));
                *(unsigned int*)(smem + pix*512 + ((n0*2 + lm*4) ^ ((pix & 31) << 4))) = pk;
            }
    } else {
        // fallback: fp32 VALU layer 1, raw weights, direct permuted h1 writes
        const int gp = pixbase + lane;
        float xv[12];
        #pragma unroll
        for (int k = 0; k < 3; ++k) xv[k]     = sph[k*NPIX + gp];
        #pragma unroll
        for (int k = 0; k < 3; ++k) xv[3 + k] = nrm[k*NPIX + gp];
        #pragma unroll
        for (int k = 0; k < 3; ++k) xv[6 + k] = pc [k*NPIX + gp];
        #pragma unroll
        for (int k = 0; k < 3; ++k) xv[9 + k] = vd [k*NPIX + gp];
        #pragma unroll
        for (int c = 0; c < 32; ++c) {
            const int cc = n0 + c;
            float a = b1[cc];
            #pragma unroll
            for (int k = 0; k < 12; ++k) a += W1[cc*12 + k] * xv[k];
            const int kp = n0 + ((c & 15) << 1) + (c >> 4);
            *(unsigned short*)(smem + lane*512 + ((kp*2) ^ ((lane & 31) << 4))) =
                f2bf(__sinf(30.0f * a));
        }
    }
    __syncthreads();

    // ================= layer 2: K-loop (K'=256), wave tile 64pix x 32ch =================
    #pragma unroll
    for (int nf = 0; nf < 2; ++nf) {
        const float bv = PRE ? b2[n0 + nf*16 + lm] * SCALE : b2[n0 + nf*16 + lm];
        #pragma unroll
        for (int mf = 0; mf < 4; ++mf) acc[mf][nf] = (f32x4){bv, bv, bv, bv};
    }

    if constexpr (PRE) {
        const unsigned short* bp = W2b + (n0 + lm)*CH + lg*8;
        #pragma unroll
        for (int k0i = 0; k0i < 8; ++k0i) {
            bf16x8 bfr[2];
            #pragma unroll
            for (int nf = 0; nf < 2; ++nf)
                bfr[nf] = *(const bf16x8*)(bp + nf*16*CH + k0i*32);
            bf16x8 afr[4];
            #pragma unroll
            for (int mf = 0; mf < 4; ++mf) {
                const int pr = mf*16 + lm;
                afr[mf] = *(const bf16x8*)(smem + pr*512 +
                              ((k0i*64 + lg*16) ^ ((pr & 31) << 4)));
            }
            #pragma unroll
            for (int nf = 0; nf < 2; ++nf)
                #pragma unroll
                for (int mf = 0; mf < 4; ++mf)
                    acc[mf][nf] = __builtin_amdgcn_mfma_f32_16x16x32_bf16(
                                      afr[mf], bfr[nf], acc[mf][nf], 0, 0, 0);
        }
    } else {
        #pragma unroll
        for (int k0i = 0; k0i < 8; ++k0i) {
            bf16x8 afr[4];
            #pragma unroll
            for (int mf = 0; mf < 4; ++mf) {
                const int pr = mf*16 + lm;
                afr[mf] = *(const bf16x8*)(smem + pr*512 +
                              ((k0i*64 + lg*16) ^ ((pr & 31) << 4)));
            }
            #pragma unroll
            for (int nf = 0; nf < 2; ++nf) {
                bf16x8 t;
                #pragma unroll
                for (int j = 0; j < 8; ++j) {
                    const int kp = k0i*32 + lg*8 + j;
                    const int kr = (kp & ~31) | ((kp & 1) << 4) | ((kp >> 1) & 15);
                    t[j] = (short)f2bf(W2f[(n0 + nf*16 + lm)*CH + kr]);
                }
                #pragma unroll
                for (int mf = 0; mf < 4; ++mf)
                    acc[mf][nf] = __builtin_amdgcn_mfma_f32_16x16x32_bf16(
                                      afr[mf], t, acc[mf][nf], 0, 0, 0);
            }
        }
    }
    __syncthreads();   // all h1 reads done

    // ================= h2 -> packed pair write =================
    #pragma unroll
    for (int mf = 0; mf < 4; ++mf)
        #pragma unroll
        for (int r = 0; r < 4; ++r) {
            const int pix = mf*16 + lg*4 + r;
            unsigned int pk;
            if constexpr (PRE)
                pk = pkbf(sinrev(acc[mf][0][r]), sinrev(acc[mf][1][r]));
            else
                pk = pkbf(__sinf(30.0f*acc[mf][0][r]), __sinf(30.0f*acc[mf][1][r]));
            *(unsigned int*)(smem + pix*512 + ((n0*2 + lm*4) ^ ((pix & 31) << 4))) = pk;
        }
    __syncthreads();

    // ================= layer 4 (wave 0 only): 64pix x 3, K'=256 =================
    if (wave == 0) {
        const float b4v = (lm < 3) ? (PRE ? b4[lm] * SCALE : b4[lm]) : 0.0f;
        f32x4 d[4];
        #pragma unroll
        for (int mf = 0; mf < 4; ++mf) d[mf] = (f32x4){b4v, b4v, b4v, b4v};

        #pragma unroll
        for (int k0i = 0; k0i < 8; ++k0i) {
            bf16x8 b4f;
            if constexpr (PRE) {
                b4f = *(const bf16x8*)(W4b + lm*CH + k0i*32 + lg*8);  // rows 3..15 zero
            } else {
                #pragma unroll
                for (int j = 0; j < 8; ++j) {
                    const int kp = k0i*32 + lg*8 + j;
                    const int kr = (kp & ~31) | ((kp & 1) << 4) | ((kp >> 1) & 15);
                    b4f[j] = (lm < 3) ? (short)f2bf(W4f[lm*CH + kr]) : (short)0;
                }
            }
            bf16x8 afr[4];
            #pragma unroll
            for (int mf = 0; mf < 4; ++mf) {
                const int pr = mf*16 + lm;
                afr[mf] = *(const bf16x8*)(smem + pr*512 +
                              ((k0i*64 + lg*16) ^ ((pr & 31) << 4)));
            }
            #pragma unroll
            for (int mf = 0; mf < 4; ++mf)
                d[mf] = __builtin_amdgcn_mfma_f32_16x16x32_bf16(
                            afr[mf], b4f, d[mf], 0, 0, 0);
        }

        if (lm < 3) {
            #pragma unroll
            for (int mf = 0; mf < 4; ++mf)
                #pragma unroll
                for (int r = 0; r < 4; ++r) {
                    const int pix = mf*16 + lg*4 + r;
                    const int gi  = lm*NPIX + pixbase + pix;
                    const float sv = PRE ? sinrev(d[mf][r]) : __sinf(30.0f * d[mf][r]);
                    out[gi] = z[gi] + 0.5f * sv;
                }
        }
    }
}

extern "C" void kernel_launch(void* const* d_in, const int* in_sizes, int n_in,
                              void* d_out, int out_size, void* d_ws, size_t ws_size,
                              hipStream_t stream) {
    const float* z   = (const float*)d_in[0];
    const float* nrm = (const float*)d_in[1];
    // d_in[2] = ad : unused by the reference
    const float* s   = (const float*)d_in[3];
    const float* pc  = (const float*)d_in[4];
    const float* vd  = (const float*)d_in[5];
    const float* W1  = (const float*)d_in[6];
    const float* b1  = (const float*)d_in[7];
    const float* W2  = (const float*)d_in[8];
    const float* b2  = (const float*)d_in[9];
    const float* W4  = (const float*)d_in[10];
    const float* b4  = (const float*)d_in[11];
    float* out = (float*)d_out;

    const size_t need = (size_t)(CH*CH + 16*CH + 16*CH) * sizeof(unsigned short); // 144 KB
    if (ws_size >= need) {
        unsigned short* W2b = (unsigned short*)d_ws;
        unsigned short* W1b = W2b + CH*CH;
        unsigned short* W4b = W1b + 16*CH;
        conv_weights<<<dim3(257), dim3(256), 0, stream>>>(W1, W2, W4, W2b, W1b, W4b);
        rendernet5<true><<<dim3(NPIX/64), dim3(512), 0, stream>>>(
            z, nrm, s, pc, vd, W1, b1, W2, W2b, W1b, b2, W4, W4b, b4, out);
    } else {
        rendernet5<false><<<dim3(NPIX/64), dim3(512), 0, stream>>>(
            z, nrm, s, pc, vd, W1, b1, W2, nullptr, nullptr, b2, W4, nullptr, b4, out);
    }
}